// Round 3
// baseline (33238.376 us; speedup 1.0000x reference)
//
#include <hip/hip_runtime.h>
#include <hip/hip_bf16.h>
#include <stdint.h>

// DBLSTM: B=32, T=1024, D=256, H=256
//  weights -> bf16 GEMM-B layout [K/8][N][8] and scan U-fragment layouts
//  G1/G2: xp1 = x@W + b (per direction; backward reverses time in A row map)
//  scan1/scan2: persistent 8 WGs/dir; h exchanged via TAGGED u32 words
//    (value<<16 | step) through relaxed agent-scope atomics -> no fences,
//    no flags, no barriers; parity double-buffer for no-clobber.
//  G3/G4: xp2 = [x, hs1] @ [Wx;Wh]  (K=512 concat GEMM)
//  scan2 writes y_t2 / y_net2 directly into d_out.

typedef unsigned short u16;
typedef unsigned int   u32;
typedef __attribute__((ext_vector_type(8))) short s8v;   // 8 x bf16 fragment
typedef __attribute__((ext_vector_type(4))) float f4v;   // MFMA accumulator

__device__ __forceinline__ f4v mfma16(s8v a, s8v b, f4v c) {
  return __builtin_amdgcn_mfma_f32_16x16x32_bf16(a, b, c, 0, 0, 0);
}

__device__ __forceinline__ u16 f2bf(float f) {
  u32 u = __float_as_uint(f);
  return (u16)((u + 0x7FFFu + ((u >> 16) & 1u)) >> 16);
}
__device__ __forceinline__ float bf2f(u16 h) {
  return __uint_as_float(((u32)h) << 16);
}
__device__ __forceinline__ float sigm(float x) {
  return __builtin_amdgcn_rcpf(1.0f + __expf(-x));
}
__device__ __forceinline__ float tanh_f(float x) {
  return 1.0f - 2.0f * __builtin_amdgcn_rcpf(__expf(2.0f * x) + 1.0f);
}

// ---------------- converts ----------------

// W (4,256,256) f32 -> Bg[kg][g*256+h][8] bf16 (GEMM B, k-packed)
__global__ void k_wconv(const float* __restrict__ src, u16* __restrict__ dst) {
  int o = blockIdx.x * 256 + threadIdx.x;     // 262144 total
  int j = o & 7, col = (o >> 3) & 1023, kg = o >> 13;
  int g = col >> 8, h = col & 255, k = (kg << 3) + j;
  dst[o] = f2bf(src[((g << 8) + k) * 256 + h]);
}

// l1_U (4,256,256) -> scan1 fragment layout [wg8][hcx2][fi32=g*8+s][lane64][j8]
__global__ void k_uconv1(const float* __restrict__ src, u16* __restrict__ dst) {
  int o = blockIdx.x * 256 + threadIdx.x;     // 262144 total
  int j = o & 7, l = (o >> 3) & 63, fi = (o >> 9) & 31, hcx = (o >> 14) & 1, wg = o >> 15;
  int g = fi >> 3, s = fi & 7;
  int k = s * 32 + ((l >> 4) << 3) + j;
  int h = wg * 32 + hcx * 16 + (l & 15);
  dst[o] = f2bf(src[((g << 8) + k) * 256 + h]);
}

// l2_U[0] (256,256) -> scan2 fragment layout [wg8][nt2][s8][lane64][j8]
__global__ void k_uconv2(const float* __restrict__ src, u16* __restrict__ dst) {
  int o = blockIdx.x * 256 + threadIdx.x;     // 65536 total
  int j = o & 7, l = (o >> 3) & 63, s = (o >> 9) & 7, nt = (o >> 12) & 1, wg = o >> 13;
  int k = s * 32 + ((l >> 4) << 3) + j;
  int h = wg * 32 + nt * 16 + (l & 15);
  dst[o] = f2bf(src[k * 256 + h]);
}

__global__ void k_canary(float* __restrict__ out, int n) {
  int i = blockIdx.x * 256 + threadIdx.x;
  if (i < n) out[i] = 1.0e9f;
}

// ---------------- GEMM: C[M=32768][N=1024] = A @ B (+bias), bf16 out -------
// A rows r: t = r>>5, b = r&31. k<256 -> X f32 at x[b][rev?1023-t:t][k] (cvt bf16).
// k>=256 -> A1 bf16 (hs1, [t][b][h]). Bg: [K/8][1024][8]. C bf16 [r][n].
__global__ __launch_bounds__(256) void k_gemm(
    const float* __restrict__ X, const u16* __restrict__ A1,
    const u16* __restrict__ Bg, const float* __restrict__ bias,
    u16* __restrict__ C, int K, int rev)
{
  __shared__ __align__(16) u16 At[128 * 32];     // [row][k]
  __shared__ __align__(16) u16 Bt[4 * 128 * 8];  // [kg][n][8]
  const int tid = threadIdx.x, l = tid & 63, w = tid >> 6;
  const int wm = w >> 1, wn = w & 1;
  const int m0 = blockIdx.y * 128, n0 = blockIdx.x * 128;
  f4v z = {0.f, 0.f, 0.f, 0.f};
  f4v acc[4][4];
  #pragma unroll
  for (int a = 0; a < 4; ++a)
    #pragma unroll
    for (int b = 0; b < 4; ++b) acc[a][b] = z;

  const int nk = K >> 5;
  for (int ki = 0; ki < nk; ++ki) {
    #pragma unroll
    for (int i = 0; i < 2; ++i) {
      int id = tid + (i << 8);
      int row = id >> 2, kc = id & 3;
      int ks = (ki << 5) + (kc << 3);
      int gm = m0 + row;
      if (ks < 256) {
        int tt = gm >> 5, bb = gm & 31;
        int tsrc = rev ? (1023 - tt) : tt;
        const float4* s = (const float4*)(X + ((size_t)bb * 1024 + tsrc) * 256 + ks);
        float4 f0 = s[0], f1 = s[1];
        alignas(16) u16 tmp[8];
        tmp[0] = f2bf(f0.x); tmp[1] = f2bf(f0.y); tmp[2] = f2bf(f0.z); tmp[3] = f2bf(f0.w);
        tmp[4] = f2bf(f1.x); tmp[5] = f2bf(f1.y); tmp[6] = f2bf(f1.z); tmp[7] = f2bf(f1.w);
        *(uint4*)&At[id << 3] = *(const uint4*)tmp;
      } else {
        const u16* s = A1 + (size_t)gm * 256 + (ks - 256);
        *(uint4*)&At[id << 3] = *(const uint4*)s;
      }
      int kg = id >> 7, n = id & 127;
      const u16* s2 = Bg + (((size_t)(ki * 4 + kg) * 1024) + n0 + n) * 8;
      *(uint4*)&Bt[id << 3] = *(const uint4*)s2;
    }
    __syncthreads();
    s8v af[4], bf[4];
    #pragma unroll
    for (int mt = 0; mt < 4; ++mt)
      af[mt] = *(const s8v*)&At[((wm * 64 + mt * 16 + (l & 15)) * 32) + ((l >> 4) << 3)];
    #pragma unroll
    for (int nt = 0; nt < 4; ++nt)
      bf[nt] = *(const s8v*)&Bt[(((l >> 4) * 128) + wn * 64 + nt * 16 + (l & 15)) << 3];
    #pragma unroll
    for (int mt = 0; mt < 4; ++mt)
      #pragma unroll
      for (int nt = 0; nt < 4; ++nt)
        acc[mt][nt] = mfma16(af[mt], bf[nt], acc[mt][nt]);
    __syncthreads();
  }

  float bv[4];
  #pragma unroll
  for (int nt = 0; nt < 4; ++nt)
    bv[nt] = bias ? bias[n0 + wn * 64 + nt * 16 + (l & 15)] : 0.f;
  #pragma unroll
  for (int mt = 0; mt < 4; ++mt)
    #pragma unroll
    for (int nt = 0; nt < 4; ++nt)
      #pragma unroll
      for (int rr = 0; rr < 4; ++rr) {
        int row = m0 + wm * 64 + mt * 16 + ((l >> 4) << 2) + rr;
        int col = n0 + wn * 64 + nt * 16 + (l & 15);
        C[(size_t)row * 1024 + col] = f2bf(acc[mt][nt][rr] + bv[nt]);
      }
}

// ---------------- scans (tagged-word protocol) ----------------
// hbuf (u32): per dir 2 parity x [32 rows][256 cols]. word = (bf16<<16)|tag.
// tag of h published at end of step t is (t+1); readers at step t expect tag t.
// Relaxed agent-scope atomics = single cache-bypassing loads/stores; no fences.

__device__ __forceinline__ void ldxp16(const u16* __restrict__ xp, int t,
                                       int rowbase, int hc, u16* q) {
  const u16* p = xp + ((size_t)t << 15);
  #pragma unroll
  for (int g = 0; g < 4; ++g)
    #pragma unroll
    for (int rr = 0; rr < 4; ++rr)
      q[g * 4 + rr] = p[(rowbase + rr) * 1024 + g * 256 + hc];
}

// load + validate the 64 tagged words -> 8 A-fragments (retries until fresh)
__device__ __forceinline__ void ld_h_frags(const u32* hr, u32 tag, s8v* af) {
  #pragma unroll 1
  for (;;) {
    u32 bad = 0;
    #pragma unroll
    for (int s = 0; s < 8; ++s) {
      u32 w[8];
      #pragma unroll
      for (int j = 0; j < 8; ++j)
        w[j] = __hip_atomic_load(hr + s * 32 + j, __ATOMIC_RELAXED,
                                 __HIP_MEMORY_SCOPE_AGENT);
      #pragma unroll
      for (int j = 0; j < 8; ++j) bad |= (w[j] ^ tag) & 0xffffu;
      union { u32 d[4]; s8v v; } pk;
      #pragma unroll
      for (int j = 0; j < 4; ++j)
        pk.d[j] = (w[2 * j] >> 16) | (w[2 * j + 1] & 0xffff0000u);
      af[s] = pk.v;
    }
    if (!__any(bad != 0)) break;
  }
}

// scan1: 16 blocks (dir = bid>>3, wg = bid&7), 256 thr = 4 free-running waves.
__global__ __launch_bounds__(256, 1) void k_scan1(
    const u16* __restrict__ xp_f, const u16* __restrict__ xp_b,
    const u16* __restrict__ Uf_f, const u16* __restrict__ Uf_b,
    u16* __restrict__ hs_f, u16* __restrict__ hs_b,
    u32* hbuf)
{
  const int bid = blockIdx.x;
  const int dir = bid >> 3, wg = bid & 7;
  const int tid = threadIdx.x, l = tid & 63, wv = tid >> 6;
  const int mt = wv >> 1, hcx = wv & 1;
  const u16* xp = dir ? xp_b : xp_f;
  const u16* Uf = dir ? Uf_b : Uf_f;
  u16* hs = dir ? hs_b : hs_f;
  u32* hb = hbuf + dir * 16384;            // 2 parity x 8192 words

  const int hc = wg * 32 + hcx * 16 + (l & 15);
  const int rowbase = mt * 16 + ((l >> 4) << 2);   // C/D rows (output)
  const int arow = (mt * 16 + (l & 15)) * 256;     // A row offset (words)
  const int kcol = (l >> 4) << 3;

  s8v uf[32];                              // [g*8+s]
  #pragma unroll
  for (int fi = 0; fi < 32; ++fi)
    uf[fi] = *(const s8v*)(Uf + ((((wg * 2 + hcx) * 32 + fi) * 64 + l) << 3));

  float c[4] = {0.f, 0.f, 0.f, 0.f};
  u16 xq[16];
  ldxp16(xp, 0, rowbase, hc, xq);

  #pragma unroll 1
  for (int t = 0; t < 1024; ++t) {
    u16 xc[16];
    #pragma unroll
    for (int i = 0; i < 16; ++i) xc[i] = xq[i];
    if (t < 1023) ldxp16(xp, t + 1, rowbase, hc, xq);

    f4v zz = {0.f, 0.f, 0.f, 0.f};
    f4v acc[4];
    #pragma unroll
    for (int g = 0; g < 4; ++g) acc[g] = zz;

    if (t > 0) {
      const u32* hr = hb + ((t & 1) << 13) + arow + kcol;
      s8v af[8];
      ld_h_frags(hr, (u32)t, af);
      #pragma unroll
      for (int s = 0; s < 8; ++s)
        #pragma unroll
        for (int g = 0; g < 4; ++g)
          acc[g] = mfma16(af[s], uf[g * 8 + s], acc[g]);
    }

    u32* hw = hb + (((t + 1) & 1) << 13);
    const u32 wtag = (u32)(t + 1);
    #pragma unroll
    for (int rr = 0; rr < 4; ++rr) {
      const int b = rowbase + rr;
      float si = sigm(bf2f(xc[0 * 4 + rr]) + acc[0][rr]);
      float sf = sigm(bf2f(xc[1 * 4 + rr]) + acc[1][rr]);
      float sg = sigm(bf2f(xc[2 * 4 + rr]) + acc[2][rr]);
      float so = sigm(bf2f(xc[3 * 4 + rr]) + acc[3][rr]);
      c[rr] = sf + c[rr] + si * sg;
      float h = so + tanh_f(c[rr]);
      u16 hv = f2bf(h);
      __hip_atomic_store(hw + b * 256 + hc, ((u32)hv << 16) | wtag,
                         __ATOMIC_RELAXED, __HIP_MEMORY_SCOPE_AGENT);
      hs[((t << 5) + b) * 256 + hc] = hv;
    }
  }
}

// scan2: hu = h@U[0] + b[0] broadcast across gates; writes y_net2/y_t2 to d_out.
__global__ __launch_bounds__(256, 1) void k_scan2(
    const u16* __restrict__ xp_f, const u16* __restrict__ xp_b,
    const u16* __restrict__ Uf_f, const u16* __restrict__ Uf_b,
    const float* __restrict__ b2_f, const float* __restrict__ b2_b,
    float* __restrict__ out,
    u32* hbuf)
{
  const int bid = blockIdx.x;
  const int dir = bid >> 3, wg = bid & 7;
  const int tid = threadIdx.x, l = tid & 63, wv = tid >> 6;
  const int mt = wv >> 1, nt = wv & 1;
  const u16* xp = dir ? xp_b : xp_f;
  const u16* Uf = dir ? Uf_b : Uf_f;
  const float* b2 = dir ? b2_b : b2_f;
  u32* hb = hbuf + dir * 16384;

  const int hc = wg * 32 + nt * 16 + (l & 15);
  const int rowbase = mt * 16 + ((l >> 4) << 2);
  const int arow = (mt * 16 + (l & 15)) * 256;
  const int kcol = (l >> 4) << 3;
  const float bv = b2[hc];
  const int jj = (dir ? 256 : 0) + hc;

  s8v uf[8];
  #pragma unroll
  for (int s = 0; s < 8; ++s)
    uf[s] = *(const s8v*)(Uf + ((((wg * 2 + nt) * 8 + s) * 64 + l) << 3));

  float c[4] = {0.f, 0.f, 0.f, 0.f};
  u16 xq[16];
  ldxp16(xp, 0, rowbase, hc, xq);

  #pragma unroll 1
  for (int t = 0; t < 1024; ++t) {
    u16 xc[16];
    #pragma unroll
    for (int i = 0; i < 16; ++i) xc[i] = xq[i];
    if (t < 1023) ldxp16(xp, t + 1, rowbase, hc, xq);

    f4v acc = {0.f, 0.f, 0.f, 0.f};
    if (t > 0) {
      const u32* hr = hb + ((t & 1) << 13) + arow + kcol;
      s8v af[8];
      ld_h_frags(hr, (u32)t, af);
      #pragma unroll
      for (int s = 0; s < 8; ++s)
        acc = mfma16(af[s], uf[s], acc);
    }

    u32* hw = hb + (((t + 1) & 1) << 13);
    const u32 wtag = (u32)(t + 1);
    const int tout = dir ? (1023 - t) : t;
    #pragma unroll
    for (int rr = 0; rr < 4; ++rr) {
      const int b = rowbase + rr;
      float hu = acc[rr] + bv;
      float si = sigm(bf2f(xc[0 * 4 + rr]) + hu);
      float sf = sigm(bf2f(xc[1 * 4 + rr]) + hu);
      float sg = sigm(bf2f(xc[2 * 4 + rr]) + hu);
      float so = sigm(bf2f(xc[3 * 4 + rr]) + hu);
      c[rr] = sf + c[rr] + si * sg;
      float h = so + tanh_f(c[rr]);
      __hip_atomic_store(hw + b * 256 + hc, ((u32)f2bf(h) << 16) | wtag,
                         __ATOMIC_RELAXED, __HIP_MEMORY_SCOPE_AGENT);
      out[16384 + ((size_t)b * 1024 + tout) * 512 + jj] = h;   // y_net2
      if (t == 1023) out[b * 512 + jj] = h;                    // y_t2
    }
  }
}

// ---------------- host ----------------
extern "C" void kernel_launch(void* const* d_in, const int* in_sizes, int n_in,
                              void* d_out, int out_size, void* d_ws, size_t ws_size,
                              hipStream_t stream)
{
  const float* x      = (const float*)d_in[0];
  const float* l1_W   = (const float*)d_in[1];
  const float* l1_U   = (const float*)d_in[2];
  const float* l1_b   = (const float*)d_in[3];
  const float* l1_Wb  = (const float*)d_in[4];
  const float* l1_Ub  = (const float*)d_in[5];
  const float* l1_bb  = (const float*)d_in[6];
  const float* l2_Wx  = (const float*)d_in[7];
  const float* l2_Wh  = (const float*)d_in[8];
  const float* l2_U   = (const float*)d_in[9];
  const float* l2_b   = (const float*)d_in[10];
  const float* l2_Wxb = (const float*)d_in[11];
  const float* l2_Whb = (const float*)d_in[12];
  const float* l2_Ub  = (const float*)d_in[13];
  const float* l2_bb  = (const float*)d_in[14];

  char* p0 = (char*)d_ws;
  char* p = p0;
  auto alloc = [&](size_t bytes) {
    char* r = p; p += (bytes + 255) & ~(size_t)255; return r;
  };
  u16*   xpf   = (u16*)  alloc(33554432ull * 2);   // 64 MB
  u16*   xpb   = (u16*)  alloc(33554432ull * 2);   // 64 MB
  u16*   hs1f  = (u16*)  alloc(8388608ull * 2);    // 16 MB
  u16*   hs1b  = (u16*)  alloc(8388608ull * 2);    // 16 MB
  u16*   W1f   = (u16*)  alloc(262144ull * 2);
  u16*   W1b   = (u16*)  alloc(262144ull * 2);
  u16*   Wc2f  = (u16*)  alloc(524288ull * 2);
  u16*   Wc2b  = (u16*)  alloc(524288ull * 2);
  u16*   Uf1f  = (u16*)  alloc(262144ull * 2);
  u16*   Uf1b  = (u16*)  alloc(262144ull * 2);
  u16*   Uf2f  = (u16*)  alloc(65536ull * 2);
  u16*   Uf2b  = (u16*)  alloc(65536ull * 2);
  u32*   hbuf1 = (u32*)  alloc(32768ull * 4);      // tagged h, scan1
  u32*   hbuf2 = (u32*)  alloc(32768ull * 4);      // tagged h, scan2
  if ((size_t)(p - p0) > ws_size) {                // ws canary: absmax ~1e9
    k_canary<<<(out_size + 255) / 256, 256, 0, stream>>>((float*)d_out, out_size);
    return;
  }

  k_wconv<<<1024, 256, 0, stream>>>(l1_W,   W1f);
  k_wconv<<<1024, 256, 0, stream>>>(l1_Wb,  W1b);
  k_wconv<<<1024, 256, 0, stream>>>(l2_Wx,  Wc2f);
  k_wconv<<<1024, 256, 0, stream>>>(l2_Wh,  Wc2f + 262144);
  k_wconv<<<1024, 256, 0, stream>>>(l2_Wxb, Wc2b);
  k_wconv<<<1024, 256, 0, stream>>>(l2_Whb, Wc2b + 262144);
  k_uconv1<<<1024, 256, 0, stream>>>(l1_U,  Uf1f);
  k_uconv1<<<1024, 256, 0, stream>>>(l1_Ub, Uf1b);
  k_uconv2<<<256, 256, 0, stream>>>(l2_U,  Uf2f);
  k_uconv2<<<256, 256, 0, stream>>>(l2_Ub, Uf2b);

  dim3 gg(8, 256);
  k_gemm<<<gg, 256, 0, stream>>>(x, nullptr, W1f, l1_b,  xpf, 256, 0);
  k_gemm<<<gg, 256, 0, stream>>>(x, nullptr, W1b, l1_bb, xpb, 256, 1);

  k_scan1<<<16, 256, 0, stream>>>(xpf, xpb, Uf1f, Uf1b, hs1f, hs1b, hbuf1);

  k_gemm<<<gg, 256, 0, stream>>>(x, hs1f, Wc2f, nullptr, xpf, 512, 0);
  k_gemm<<<gg, 256, 0, stream>>>(x, hs1b, Wc2b, nullptr, xpb, 512, 1);

  k_scan2<<<16, 256, 0, stream>>>(xpf, xpb, Uf2f, Uf2b, l2_b, l2_bb,
                                  (float*)d_out, hbuf2);
}

// Round 5
// 9123.103 us; speedup vs baseline: 3.6433x; 3.6433x over previous
//
#include <hip/hip_runtime.h>
#include <hip/hip_bf16.h>
#include <stdint.h>

// DBLSTM: B=32, T=1024, D=256, H=256
//  scan1/scan2: 8 persistent WGs per direction; h exchanged as tagged u32
//  words ((bf16<<16)|step) through the DEVICE COHERENT POINT:
//    stores: __hip_atomic_store relaxed/agent  (r3-proven: sc0 sc1 write-through)
//    loads:  inline-asm global_load_dwordx4 sc0 sc1 (16 in flight, 1 vmcnt)
//  Tags self-validate -> no fences, no flags, no barriers. Parity double
//  buffer for no-clobber. Retry cap poisons with NaN (loud failure, no hang).
//  GEMMs: xp1 = x@W + b ; xp2 = [x, hs1] @ [Wx;Wh] (K=512), bf16 MFMA tiles.
//  scan2 writes y_t2 / y_net2 directly into d_out.

typedef unsigned short u16;
typedef unsigned int   u32;
typedef __attribute__((ext_vector_type(8))) short s8v;   // 8 x bf16 fragment
typedef __attribute__((ext_vector_type(4))) float f4v;   // MFMA accumulator
typedef __attribute__((ext_vector_type(4))) u32   u32x4;

__device__ __forceinline__ f4v mfma16(s8v a, s8v b, f4v c) {
  return __builtin_amdgcn_mfma_f32_16x16x32_bf16(a, b, c, 0, 0, 0);
}

__device__ __forceinline__ u16 f2bf(float f) {
  u32 u = __float_as_uint(f);
  return (u16)((u + 0x7FFFu + ((u >> 16) & 1u)) >> 16);
}
__device__ __forceinline__ float bf2f(u16 h) {
  return __uint_as_float(((u32)h) << 16);
}
__device__ __forceinline__ float sigm(float x) {
  return __builtin_amdgcn_rcpf(1.0f + __expf(-x));
}
__device__ __forceinline__ float tanh_f(float x) {
  return 1.0f - 2.0f * __builtin_amdgcn_rcpf(__expf(2.0f * x) + 1.0f);
}

// ---------------- converts ----------------

// W (4,256,256) f32 -> Bg[kg][g*256+h][8] bf16 (GEMM B, k-packed)
__global__ void k_wconv(const float* __restrict__ src, u16* __restrict__ dst) {
  int o = blockIdx.x * 256 + threadIdx.x;     // 262144 total
  int j = o & 7, col = (o >> 3) & 1023, kg = o >> 13;
  int g = col >> 8, h = col & 255, k = (kg << 3) + j;
  dst[o] = f2bf(src[((g << 8) + k) * 256 + h]);
}

// l1_U (4,256,256) -> scan1 fragment layout [wg8][hcx2][fi32=g*8+s][lane64][j8]
__global__ void k_uconv1(const float* __restrict__ src, u16* __restrict__ dst) {
  int o = blockIdx.x * 256 + threadIdx.x;     // 262144 total
  int j = o & 7, l = (o >> 3) & 63, fi = (o >> 9) & 31, hcx = (o >> 14) & 1, wg = o >> 15;
  int g = fi >> 3, s = fi & 7;
  int k = s * 32 + ((l >> 4) << 3) + j;
  int h = wg * 32 + hcx * 16 + (l & 15);
  dst[o] = f2bf(src[((g << 8) + k) * 256 + h]);
}

// l2_U[0] (256,256) -> scan2 fragment layout [wg8][nt2][s8][lane64][j8]
__global__ void k_uconv2(const float* __restrict__ src, u16* __restrict__ dst) {
  int o = blockIdx.x * 256 + threadIdx.x;     // 65536 total
  int j = o & 7, l = (o >> 3) & 63, s = (o >> 9) & 7, nt = (o >> 12) & 1, wg = o >> 13;
  int k = s * 32 + ((l >> 4) << 3) + j;
  int h = wg * 32 + nt * 16 + (l & 15);
  dst[o] = f2bf(src[k * 256 + h]);
}

__global__ void k_canary(float* __restrict__ out, int n) {
  int i = blockIdx.x * 256 + threadIdx.x;
  if (i < n) out[i] = 1.0e9f;
}

// ---------------- GEMM: C[M=32768][N=1024] = A @ B (+bias), bf16 out -------
__global__ __launch_bounds__(256) void k_gemm(
    const float* __restrict__ X, const u16* __restrict__ A1,
    const u16* __restrict__ Bg, const float* __restrict__ bias,
    u16* __restrict__ C, int K, int rev)
{
  __shared__ __align__(16) u16 At[128 * 32];     // [row][k]
  __shared__ __align__(16) u16 Bt[4 * 128 * 8];  // [kg][n][8]
  const int tid = threadIdx.x, l = tid & 63, w = tid >> 6;
  const int wm = w >> 1, wn = w & 1;
  const int m0 = blockIdx.y * 128, n0 = blockIdx.x * 128;
  f4v z = {0.f, 0.f, 0.f, 0.f};
  f4v acc[4][4];
  #pragma unroll
  for (int a = 0; a < 4; ++a)
    #pragma unroll
    for (int b = 0; b < 4; ++b) acc[a][b] = z;

  const int nk = K >> 5;
  for (int ki = 0; ki < nk; ++ki) {
    #pragma unroll
    for (int i = 0; i < 2; ++i) {
      int id = tid + (i << 8);
      int row = id >> 2, kc = id & 3;
      int ks = (ki << 5) + (kc << 3);
      int gm = m0 + row;
      if (ks < 256) {
        int tt = gm >> 5, bb = gm & 31;
        int tsrc = rev ? (1023 - tt) : tt;
        const float4* s = (const float4*)(X + ((size_t)bb * 1024 + tsrc) * 256 + ks);
        float4 f0 = s[0], f1 = s[1];
        alignas(16) u16 tmp[8];
        tmp[0] = f2bf(f0.x); tmp[1] = f2bf(f0.y); tmp[2] = f2bf(f0.z); tmp[3] = f2bf(f0.w);
        tmp[4] = f2bf(f1.x); tmp[5] = f2bf(f1.y); tmp[6] = f2bf(f1.z); tmp[7] = f2bf(f1.w);
        *(uint4*)&At[id << 3] = *(const uint4*)tmp;
      } else {
        const u16* s = A1 + (size_t)gm * 256 + (ks - 256);
        *(uint4*)&At[id << 3] = *(const uint4*)s;
      }
      int kg = id >> 7, n = id & 127;
      const u16* s2 = Bg + (((size_t)(ki * 4 + kg) * 1024) + n0 + n) * 8;
      *(uint4*)&Bt[id << 3] = *(const uint4*)s2;
    }
    __syncthreads();
    s8v af[4], bf[4];
    #pragma unroll
    for (int mt = 0; mt < 4; ++mt)
      af[mt] = *(const s8v*)&At[((wm * 64 + mt * 16 + (l & 15)) * 32) + ((l >> 4) << 3)];
    #pragma unroll
    for (int nt = 0; nt < 4; ++nt)
      bf[nt] = *(const s8v*)&Bt[(((l >> 4) * 128) + wn * 64 + nt * 16 + (l & 15)) << 3];
    #pragma unroll
    for (int mt = 0; mt < 4; ++mt)
      #pragma unroll
      for (int nt = 0; nt < 4; ++nt)
        acc[mt][nt] = mfma16(af[mt], bf[nt], acc[mt][nt]);
    __syncthreads();
  }

  float bv[4];
  #pragma unroll
  for (int nt = 0; nt < 4; ++nt)
    bv[nt] = bias ? bias[n0 + wn * 64 + nt * 16 + (l & 15)] : 0.f;
  #pragma unroll
  for (int mt = 0; mt < 4; ++mt)
    #pragma unroll
    for (int nt = 0; nt < 4; ++nt)
      #pragma unroll
      for (int rr = 0; rr < 4; ++rr) {
        int row = m0 + wm * 64 + mt * 16 + ((l >> 4) << 2) + rr;
        int col = n0 + wn * 64 + nt * 16 + (l & 15);
        C[(size_t)row * 1024 + col] = f2bf(acc[mt][nt][rr] + bv[nt]);
      }
}

// ---------------- scans (tagged words through device coherent point) -------

__device__ __forceinline__ void ldxp16(const u16* __restrict__ xp, int t,
                                       int rowbase, int hc, u16* q) {
  const u16* p = xp + ((size_t)t << 15);
  #pragma unroll
  for (int g = 0; g < 4; ++g)
    #pragma unroll
    for (int rr = 0; rr < 4; ++rr)
      q[g * 4 + rr] = p[(rowbase + rr) * 1024 + g * 256 + hc];
}

// 16x global_load_dwordx4 sc0 sc1 (device-coherent), one vmcnt, early-clobber.
__device__ __forceinline__ void ld_h64(const u32* base, u32x4* r) {
  asm volatile(
    "global_load_dwordx4 %0, %16, off sc0 sc1\n\t"
    "global_load_dwordx4 %1, %16, off offset:16 sc0 sc1\n\t"
    "global_load_dwordx4 %2, %16, off offset:128 sc0 sc1\n\t"
    "global_load_dwordx4 %3, %16, off offset:144 sc0 sc1\n\t"
    "global_load_dwordx4 %4, %16, off offset:256 sc0 sc1\n\t"
    "global_load_dwordx4 %5, %16, off offset:272 sc0 sc1\n\t"
    "global_load_dwordx4 %6, %16, off offset:384 sc0 sc1\n\t"
    "global_load_dwordx4 %7, %16, off offset:400 sc0 sc1\n\t"
    "global_load_dwordx4 %8, %16, off offset:512 sc0 sc1\n\t"
    "global_load_dwordx4 %9, %16, off offset:528 sc0 sc1\n\t"
    "global_load_dwordx4 %10, %16, off offset:640 sc0 sc1\n\t"
    "global_load_dwordx4 %11, %16, off offset:656 sc0 sc1\n\t"
    "global_load_dwordx4 %12, %16, off offset:768 sc0 sc1\n\t"
    "global_load_dwordx4 %13, %16, off offset:784 sc0 sc1\n\t"
    "global_load_dwordx4 %14, %16, off offset:896 sc0 sc1\n\t"
    "global_load_dwordx4 %15, %16, off offset:912 sc0 sc1\n\t"
    "s_waitcnt vmcnt(0)"
    : "=&v"(r[0]), "=&v"(r[1]), "=&v"(r[2]), "=&v"(r[3]),
      "=&v"(r[4]), "=&v"(r[5]), "=&v"(r[6]), "=&v"(r[7]),
      "=&v"(r[8]), "=&v"(r[9]), "=&v"(r[10]), "=&v"(r[11]),
      "=&v"(r[12]), "=&v"(r[13]), "=&v"(r[14]), "=&v"(r[15])
    : "v"(base)
    : "memory");
}

__device__ __forceinline__ bool frags_from_tagged(const u32x4* r, u32 tag, s8v* af) {
  u32 bad = 0;
  #pragma unroll
  for (int s = 0; s < 8; ++s) {
    u32x4 a = r[2 * s], b = r[2 * s + 1];
    bad |= (a.x ^ tag) & 0xffffu; bad |= (a.y ^ tag) & 0xffffu;
    bad |= (a.z ^ tag) & 0xffffu; bad |= (a.w ^ tag) & 0xffffu;
    bad |= (b.x ^ tag) & 0xffffu; bad |= (b.y ^ tag) & 0xffffu;
    bad |= (b.z ^ tag) & 0xffffu; bad |= (b.w ^ tag) & 0xffffu;
    union { u32 d[4]; s8v v; } pk;
    pk.d[0] = (a.x >> 16) | (a.y & 0xffff0000u);
    pk.d[1] = (a.z >> 16) | (a.w & 0xffff0000u);
    pk.d[2] = (b.x >> 16) | (b.y & 0xffff0000u);
    pk.d[3] = (b.z >> 16) | (b.w & 0xffff0000u);
    af[s] = pk.v;
  }
  return !__any(bad != 0);
}

__device__ __forceinline__ void ld_h_frags(const u32* hr, u32 tag, s8v* af) {
  #pragma unroll 1
  for (int rtry = 0; ; ++rtry) {
    u32x4 r[16];
    ld_h64(hr, r);
    if (frags_from_tagged(r, tag, af)) return;
    if (rtry > (1 << 20)) {        // loud failure: NaN-poison, no silent stale
      union { u32 d[4]; s8v v; } nn;
      nn.d[0] = nn.d[1] = nn.d[2] = nn.d[3] = 0x7FC07FC0u;  // bf16 NaN pairs
      #pragma unroll
      for (int s = 0; s < 8; ++s) af[s] = nn.v;
      return;
    }
  }
}

__device__ __forceinline__ void st_tagged(u32* p, u32 v) {
  __hip_atomic_store(p, v, __ATOMIC_RELAXED, __HIP_MEMORY_SCOPE_AGENT);
}

// scan1: 16 blocks (dir = bid>>3, wg = bid&7), 256 thr = 4 free-running waves.
__global__ __launch_bounds__(256, 1) void k_scan1(
    const u16* __restrict__ xp_f, const u16* __restrict__ xp_b,
    const u16* __restrict__ Uf_f, const u16* __restrict__ Uf_b,
    u16* __restrict__ hs_f, u16* __restrict__ hs_b,
    u32* hbuf)
{
  const int bid = blockIdx.x;
  const int dir = bid >> 3, wg = bid & 7;
  const int tid = threadIdx.x, l = tid & 63, wv = tid >> 6;
  const int mt = wv >> 1, hcx = wv & 1;
  const u16* xp = dir ? xp_b : xp_f;
  const u16* Uf = dir ? Uf_b : Uf_f;
  u16* hs = dir ? hs_b : hs_f;
  u32* hb = hbuf + dir * 16384;            // 2 parity x 8192 words

  const int hc = wg * 32 + hcx * 16 + (l & 15);
  const int rowbase = mt * 16 + ((l >> 4) << 2);   // C/D rows (output)
  const int arow = (mt * 16 + (l & 15)) * 256;     // A row offset (words)
  const int kcol = (l >> 4) << 3;

  s8v uf[32];                              // [g*8+s]
  #pragma unroll
  for (int fi = 0; fi < 32; ++fi)
    uf[fi] = *(const s8v*)(Uf + ((((wg * 2 + hcx) * 32 + fi) * 64 + l) << 3));

  float c[4] = {0.f, 0.f, 0.f, 0.f};
  u16 xq[16];
  ldxp16(xp, 0, rowbase, hc, xq);

  #pragma unroll 1
  for (int t = 0; t < 1024; ++t) {
    u16 xc[16];
    #pragma unroll
    for (int i = 0; i < 16; ++i) xc[i] = xq[i];
    if (t < 1023) ldxp16(xp, t + 1, rowbase, hc, xq);

    f4v zz = {0.f, 0.f, 0.f, 0.f};
    f4v acc[4];
    #pragma unroll
    for (int g = 0; g < 4; ++g) acc[g] = zz;

    if (t > 0) {
      const u32* hr = hb + ((t & 1) << 13) + arow + kcol;
      s8v af[8];
      ld_h_frags(hr, (u32)t, af);
      #pragma unroll
      for (int s = 0; s < 8; ++s)
        #pragma unroll
        for (int g = 0; g < 4; ++g)
          acc[g] = mfma16(af[s], uf[g * 8 + s], acc[g]);
    }

    u32* hw = hb + (((t + 1) & 1) << 13);
    const u32 wtag = (u32)(t + 1);
    #pragma unroll
    for (int rr = 0; rr < 4; ++rr) {
      const int b = rowbase + rr;
      float si = sigm(bf2f(xc[0 * 4 + rr]) + acc[0][rr]);
      float sf = sigm(bf2f(xc[1 * 4 + rr]) + acc[1][rr]);
      float sg = sigm(bf2f(xc[2 * 4 + rr]) + acc[2][rr]);
      float so = sigm(bf2f(xc[3 * 4 + rr]) + acc[3][rr]);
      c[rr] = sf + c[rr] + si * sg;
      float h = so + tanh_f(c[rr]);
      u16 hv = f2bf(h);
      st_tagged(hw + b * 256 + hc, ((u32)hv << 16) | wtag);
      hs[((t << 5) + b) * 256 + hc] = hv;
    }
  }
}

// scan2: hu = h@U[0] + b[0] broadcast across gates; writes y_net2/y_t2 to d_out.
__global__ __launch_bounds__(256, 1) void k_scan2(
    const u16* __restrict__ xp_f, const u16* __restrict__ xp_b,
    const u16* __restrict__ Uf_f, const u16* __restrict__ Uf_b,
    const float* __restrict__ b2_f, const float* __restrict__ b2_b,
    float* __restrict__ out,
    u32* hbuf)
{
  const int bid = blockIdx.x;
  const int dir = bid >> 3, wg = bid & 7;
  const int tid = threadIdx.x, l = tid & 63, wv = tid >> 6;
  const int mt = wv >> 1, nt = wv & 1;
  const u16* xp = dir ? xp_b : xp_f;
  const u16* Uf = dir ? Uf_b : Uf_f;
  const float* b2 = dir ? b2_b : b2_f;
  u32* hb = hbuf + dir * 16384;

  const int hc = wg * 32 + nt * 16 + (l & 15);
  const int rowbase = mt * 16 + ((l >> 4) << 2);
  const int arow = (mt * 16 + (l & 15)) * 256;
  const int kcol = (l >> 4) << 3;
  const float bv = b2[hc];
  const int jj = (dir ? 256 : 0) + hc;

  s8v uf[8];
  #pragma unroll
  for (int s = 0; s < 8; ++s)
    uf[s] = *(const s8v*)(Uf + ((((wg * 2 + nt) * 8 + s) * 64 + l) << 3));

  float c[4] = {0.f, 0.f, 0.f, 0.f};
  u16 xq[16];
  ldxp16(xp, 0, rowbase, hc, xq);

  #pragma unroll 1
  for (int t = 0; t < 1024; ++t) {
    u16 xc[16];
    #pragma unroll
    for (int i = 0; i < 16; ++i) xc[i] = xq[i];
    if (t < 1023) ldxp16(xp, t + 1, rowbase, hc, xq);

    f4v acc = {0.f, 0.f, 0.f, 0.f};
    if (t > 0) {
      const u32* hr = hb + ((t & 1) << 13) + arow + kcol;
      s8v af[8];
      ld_h_frags(hr, (u32)t, af);
      #pragma unroll
      for (int s = 0; s < 8; ++s)
        acc = mfma16(af[s], uf[s], acc);
    }

    u32* hw = hb + (((t + 1) & 1) << 13);
    const u32 wtag = (u32)(t + 1);
    const int tout = dir ? (1023 - t) : t;
    #pragma unroll
    for (int rr = 0; rr < 4; ++rr) {
      const int b = rowbase + rr;
      float hu = acc[rr] + bv;
      float si = sigm(bf2f(xc[0 * 4 + rr]) + hu);
      float sf = sigm(bf2f(xc[1 * 4 + rr]) + hu);
      float sg = sigm(bf2f(xc[2 * 4 + rr]) + hu);
      float so = sigm(bf2f(xc[3 * 4 + rr]) + hu);
      c[rr] = sf + c[rr] + si * sg;
      float h = so + tanh_f(c[rr]);
      st_tagged(hw + b * 256 + hc, ((u32)f2bf(h) << 16) | wtag);
      out[16384 + ((size_t)b * 1024 + tout) * 512 + jj] = h;   // y_net2
      if (t == 1023) out[b * 512 + jj] = h;                    // y_t2
    }
  }
}

// ---------------- host ----------------
extern "C" void kernel_launch(void* const* d_in, const int* in_sizes, int n_in,
                              void* d_out, int out_size, void* d_ws, size_t ws_size,
                              hipStream_t stream)
{
  const float* x      = (const float*)d_in[0];
  const float* l1_W   = (const float*)d_in[1];
  const float* l1_U   = (const float*)d_in[2];
  const float* l1_b   = (const float*)d_in[3];
  const float* l1_Wb  = (const float*)d_in[4];
  const float* l1_Ub  = (const float*)d_in[5];
  const float* l1_bb  = (const float*)d_in[6];
  const float* l2_Wx  = (const float*)d_in[7];
  const float* l2_Wh  = (const float*)d_in[8];
  const float* l2_U   = (const float*)d_in[9];
  const float* l2_b   = (const float*)d_in[10];
  const float* l2_Wxb = (const float*)d_in[11];
  const float* l2_Whb = (const float*)d_in[12];
  const float* l2_Ub  = (const float*)d_in[13];
  const float* l2_bb  = (const float*)d_in[14];

  char* p0 = (char*)d_ws;
  char* p = p0;
  auto alloc = [&](size_t bytes) {
    char* r = p; p += (bytes + 255) & ~(size_t)255; return r;
  };
  u16*   xpf   = (u16*)  alloc(33554432ull * 2);   // 64 MB
  u16*   xpb   = (u16*)  alloc(33554432ull * 2);   // 64 MB
  u16*   hs1f  = (u16*)  alloc(8388608ull * 2);    // 16 MB
  u16*   hs1b  = (u16*)  alloc(8388608ull * 2);    // 16 MB
  u16*   W1f   = (u16*)  alloc(262144ull * 2);
  u16*   W1b   = (u16*)  alloc(262144ull * 2);
  u16*   Wc2f  = (u16*)  alloc(524288ull * 2);
  u16*   Wc2b  = (u16*)  alloc(524288ull * 2);
  u16*   Uf1f  = (u16*)  alloc(262144ull * 2);
  u16*   Uf1b  = (u16*)  alloc(262144ull * 2);
  u16*   Uf2f  = (u16*)  alloc(65536ull * 2);
  u16*   Uf2b  = (u16*)  alloc(65536ull * 2);
  u32*   hbuf1 = (u32*)  alloc(32768ull * 4);      // tagged h, scan1
  u32*   hbuf2 = (u32*)  alloc(32768ull * 4);      // tagged h, scan2
  if ((size_t)(p - p0) > ws_size) {                // ws canary: absmax ~1e9
    k_canary<<<(out_size + 255) / 256, 256, 0, stream>>>((float*)d_out, out_size);
    return;
  }

  k_wconv<<<1024, 256, 0, stream>>>(l1_W,   W1f);
  k_wconv<<<1024, 256, 0, stream>>>(l1_Wb,  W1b);
  k_wconv<<<1024, 256, 0, stream>>>(l2_Wx,  Wc2f);
  k_wconv<<<1024, 256, 0, stream>>>(l2_Wh,  Wc2f + 262144);
  k_wconv<<<1024, 256, 0, stream>>>(l2_Wxb, Wc2b);
  k_wconv<<<1024, 256, 0, stream>>>(l2_Whb, Wc2b + 262144);
  k_uconv1<<<1024, 256, 0, stream>>>(l1_U,  Uf1f);
  k_uconv1<<<1024, 256, 0, stream>>>(l1_Ub, Uf1b);
  k_uconv2<<<256, 256, 0, stream>>>(l2_U,  Uf2f);
  k_uconv2<<<256, 256, 0, stream>>>(l2_Ub, Uf2b);

  dim3 gg(8, 256);
  k_gemm<<<gg, 256, 0, stream>>>(x, nullptr, W1f, l1_b,  xpf, 256, 0);
  k_gemm<<<gg, 256, 0, stream>>>(x, nullptr, W1b, l1_bb, xpb, 256, 1);

  k_scan1<<<16, 256, 0, stream>>>(xpf, xpb, Uf1f, Uf1b, hs1f, hs1b, hbuf1);

  k_gemm<<<gg, 256, 0, stream>>>(x, hs1f, Wc2f, nullptr, xpf, 512, 0);
  k_gemm<<<gg, 256, 0, stream>>>(x, hs1b, Wc2b, nullptr, xpb, 512, 1);

  k_scan2<<<16, 256, 0, stream>>>(xpf, xpb, Uf2f, Uf2b, l2_b, l2_bb,
                                  (float*)d_out, hbuf2);
}